// Round 1
// baseline (21747.226 us; speedup 1.0000x reference)
//
#include <hip/hip_runtime.h>
#include <math.h>

// Problem constants
#define BB     32      // batch
#define KBM    5       // beam width
#define NR     160     // BB*KBM rows (beam-major)
#define HD     512     // hidden
#define TT     256     // encoder time steps
#define VV     5000    // vocab
#define MAXLEN 64
#define EOSID  2
#define NEGV   (-1e9f)
#define SCALEF 0.04419417382415922f  // 1/sqrt(512)

// comparator matching jax.lax.top_k stability: value desc, index asc on ties
__device__ __forceinline__ bool viBetter(float av, int ai, float bv, int bi) {
  return (av > bv) || (av == bv && ai < bi);
}

__device__ __forceinline__ void top5_insert(float tv[5], int ti[5], float x, int v) {
  if (!viBetter(x, v, tv[4], ti[4])) return;
  tv[4] = x; ti[4] = v;
#pragma unroll
  for (int q = 4; q > 0; q--) {
    if (viBetter(tv[q], ti[q], tv[q - 1], ti[q - 1])) {
      float tf = tv[q - 1]; int tx2 = ti[q - 1];
      tv[q - 1] = tv[q]; ti[q - 1] = ti[q];
      tv[q] = tf; ti[q] = tx2;
    } else break;
  }
}

// ---------------- init: h=0, tokens=0, last_tok=SOS(from input_var) -------
__global__ void k_init(float* __restrict__ h, int* __restrict__ tokens,
                       int* __restrict__ last_tok, const int* __restrict__ input_var) {
  int i = blockIdx.x * blockDim.x + threadIdx.x;
  int stride = gridDim.x * blockDim.x;
  for (int t = i; t < NR * HD; t += stride) h[t] = 0.f;
  for (int t = i; t < BB * KBM * MAXLEN; t += stride) tokens[t] = 0;
  for (int t = i; t < NR; t += stride) last_tok[t] = input_var[t / KBM];
}

// ---------------- GRU cell (fused 2 GEMMs + gates) ------------------------
// grid (512/32, 160/32) = (16,5); block 256 (tx=32 gate-cols, ty=8 row-groups)
__launch_bounds__(256)
__global__ void k_gru(const int* __restrict__ last_tok, const float* __restrict__ h,
                      const float* __restrict__ emb, const float* __restrict__ w_ih,
                      const float* __restrict__ w_hh, float* __restrict__ A_cat) {
  __shared__ float xs[32][33];
  __shared__ float hs[32][33];
  __shared__ float ws[6][32][32];   // g: 0..2 = w_ih(iz,ir,in), 3..5 = w_hh(hz,hr,hn)
  __shared__ int toks[32];
  const int tid = threadIdx.x;
  const int tx = tid & 31, ty = tid >> 5;
  const int i0 = blockIdx.x * 32;
  const int n0 = blockIdx.y * 32;
  if (tid < 32) toks[tid] = last_tok[n0 + tid];
  float acc[6][4];
#pragma unroll
  for (int g = 0; g < 6; g++)
#pragma unroll
    for (int rr = 0; rr < 4; rr++) acc[g][rr] = 0.f;

  for (int k0 = 0; k0 < HD; k0 += 32) {
    __syncthreads();
#pragma unroll
    for (int p = 0; p < 4; p++) {
      int idx = tid + p * 256;
      int r = idx >> 5, kk = idx & 31;
      xs[r][kk] = emb[(size_t)toks[r] * HD + k0 + kk];
      hs[r][kk] = h[(size_t)(n0 + r) * HD + k0 + kk];
    }
#pragma unroll
    for (int p = 0; p < 24; p++) {
      int idx = tid + p * 256;
      int g = idx >> 10;
      int rem = idx & 1023;
      int kk = rem >> 5, ii = rem & 31;
      const float* W = (g < 3) ? w_ih : w_hh;
      int gc = (g < 3) ? g : (g - 3);
      ws[g][kk][ii] = W[(size_t)(k0 + kk) * 1536 + gc * HD + i0 + ii];
    }
    __syncthreads();
#pragma unroll
    for (int kk = 0; kk < 32; kk++) {
      float w0 = ws[0][kk][tx], w1 = ws[1][kk][tx], w2 = ws[2][kk][tx];
      float w3 = ws[3][kk][tx], w4 = ws[4][kk][tx], w5 = ws[5][kk][tx];
#pragma unroll
      for (int rr = 0; rr < 4; rr++) {
        float xv = xs[ty * 4 + rr][kk];
        float hv = hs[ty * 4 + rr][kk];
        acc[0][rr] += xv * w0;
        acc[1][rr] += xv * w1;
        acc[2][rr] += xv * w2;
        acc[3][rr] += hv * w3;
        acc[4][rr] += hv * w4;
        acc[5][rr] += hv * w5;
      }
    }
  }
#pragma unroll
  for (int rr = 0; rr < 4; rr++) {
    int n = n0 + ty * 4 + rr;
    int i = i0 + tx;
    float hv = h[(size_t)n * HD + i];
    float z = 1.f / (1.f + expf(-(acc[0][rr] + acc[3][rr])));
    float r = 1.f / (1.f + expf(-(acc[1][rr] + acc[4][rr])));
    float nn = tanhf(acc[2][rr] + r * acc[5][rr]);
    A_cat[(size_t)n * 1024 + i] = (1.f - z) * nn + z * hv;
  }
}

// ---------------- attention (block per row) -------------------------------
__launch_bounds__(256)
__global__ void k_attn(float* __restrict__ A_cat, const float* __restrict__ enc) {
  __shared__ float hh[HD];
  __shared__ float sc[TT];
  __shared__ float red[256];
  const int n = blockIdx.x;
  const int b = n / KBM;
  const int tid = threadIdx.x;
  hh[tid] = A_cat[(size_t)n * 1024 + tid];
  hh[tid + 256] = A_cat[(size_t)n * 1024 + tid + 256];
  __syncthreads();
  // scores: thread tid handles encoder step t=tid
  const float* ep = enc + ((size_t)b * TT + tid) * HD;
  float acc = 0.f;
  for (int k = 0; k < HD; k += 4) {
    float4 e = *reinterpret_cast<const float4*>(ep + k);
    acc += hh[k] * e.x + hh[k + 1] * e.y + hh[k + 2] * e.z + hh[k + 3] * e.w;
  }
  float s = acc * SCALEF;
  red[tid] = s;
  __syncthreads();
  for (int off = 128; off > 0; off >>= 1) {
    if (tid < off) red[tid] = fmaxf(red[tid], red[tid + off]);
    __syncthreads();
  }
  float m = red[0];
  __syncthreads();
  float e = expf(s - m);
  red[tid] = e;
  __syncthreads();
  for (int off = 128; off > 0; off >>= 1) {
    if (tid < off) red[tid] += red[tid + off];
    __syncthreads();
  }
  float S = red[0];
  __syncthreads();
  sc[tid] = e / S;
  __syncthreads();
  // context
#pragma unroll
  for (int half = 0; half < 2; half++) {
    int i = tid + half * 256;
    float c = 0.f;
    for (int t = 0; t < TT; t++) {
      c += sc[t] * enc[((size_t)b * TT + t) * HD + i];
    }
    A_cat[(size_t)n * 1024 + HD + i] = c;
  }
}

// ---------------- output projection GEMM [160,1024]@[1024,5000] -----------
// grid (ceil(5000/128)=40, 160/32=5); block 256: tx=32 (4 cols each), ty=8 (4 rows each)
__launch_bounds__(256)
__global__ void k_gemm(const float* __restrict__ A, const float* __restrict__ Bw,
                       float* __restrict__ C) {
  __shared__ float as[32][33];
  __shared__ float bs[32][132];
  const int tid = threadIdx.x;
  const int tx = tid & 31, ty = tid >> 5;
  const int c0 = blockIdx.x * 128;
  const int n0 = blockIdx.y * 32;
  float acc[4][4];
#pragma unroll
  for (int rr = 0; rr < 4; rr++)
#pragma unroll
    for (int cc = 0; cc < 4; cc++) acc[rr][cc] = 0.f;

  for (int k0 = 0; k0 < 1024; k0 += 32) {
    __syncthreads();
#pragma unroll
    for (int p = 0; p < 4; p++) {
      int idx = tid + p * 256;
      int r = idx >> 5, kk = idx & 31;
      as[r][kk] = A[(size_t)(n0 + r) * 1024 + k0 + kk];
    }
#pragma unroll
    for (int p = 0; p < 16; p++) {
      int idx = tid + p * 256;
      int kk = idx >> 7, c = idx & 127;
      int col = c0 + c;
      bs[kk][c] = (col < VV) ? Bw[(size_t)(k0 + kk) * VV + col] : 0.f;
    }
    __syncthreads();
#pragma unroll
    for (int kk = 0; kk < 32; kk++) {
      float bv[4];
#pragma unroll
      for (int cc = 0; cc < 4; cc++) bv[cc] = bs[kk][tx * 4 + cc];
#pragma unroll
      for (int rr = 0; rr < 4; rr++) {
        float av = as[ty * 4 + rr][kk];
#pragma unroll
        for (int cc = 0; cc < 4; cc++) acc[rr][cc] += av * bv[cc];
      }
    }
  }
#pragma unroll
  for (int rr = 0; rr < 4; rr++) {
    int n = n0 + ty * 4 + rr;
#pragma unroll
    for (int cc = 0; cc < 4; cc++) {
      int c = c0 + tx * 4 + cc;
      if (c < VV) C[(size_t)n * VV + c] = acc[rr][cc];
    }
  }
}

// ---------------- joint top-k + state update (block per batch) ------------
__launch_bounds__(256)
__global__ void k_topk(const float* __restrict__ logits, float* __restrict__ cum,
                       int* __restrict__ tokens, int* __restrict__ finished,
                       int* __restrict__ lengths, int* __restrict__ last_tok,
                       float* __restrict__ h, const float* __restrict__ A_cat,
                       int di) {
  const int b = blockIdx.x;
  const int tid = threadIdx.x;
  __shared__ float red[256];
  __shared__ float sv0[256 * 5]; __shared__ int si0[256 * 5];
  __shared__ float sv1[256 * 5]; __shared__ int si1[256 * 5];
  __shared__ float candV[KBM * KBM]; __shared__ int candI[KBM * KBM];
  __shared__ float oc[KBM]; __shared__ int ofin[KBM]; __shared__ int olen[KBM];
  __shared__ int ttmp[KBM * MAXLEN];
  __shared__ int selI[KBM]; __shared__ float selV[KBM];

  if (tid < KBM) {
    oc[tid] = cum[b * KBM + tid];
    ofin[tid] = finished[b * KBM + tid];
    olen[tid] = lengths[b * KBM + tid];
  }
  for (int t = tid; t < KBM * MAXLEN; t += 256) ttmp[t] = tokens[b * KBM * MAXLEN + t];
  __syncthreads();

  for (int j = 0; j < KBM; j++) {
    if (ofin[j]) {  // uniform branch (LDS value)
      if (tid == 0) {
        float cj = oc[j];
        candV[j * KBM + 0] = cj + 0.f;     // PAD extension at zero log-prob
        candI[j * KBM + 0] = j * VV + 0;
#pragma unroll
        for (int q = 1; q < KBM; q++) {
          candV[j * KBM + q] = cj + NEGV;
          candI[j * KBM + q] = j * VV + q;
        }
      }
      continue;
    }
    const float* row = logits + (size_t)(b * KBM + j) * VV;
    // pass 1: row max + per-thread top5 of raw logits
    float tv[5]; int ti[5];
#pragma unroll
    for (int q = 0; q < 5; q++) { tv[q] = -INFINITY; ti[q] = 0x7fffffff; }
    float m = -INFINITY;
    for (int v = tid; v < VV; v += 256) {
      float x = row[v];
      m = fmaxf(m, x);
      top5_insert(tv, ti, x, v);
    }
    red[tid] = m; __syncthreads();
    for (int off = 128; off > 0; off >>= 1) {
      if (tid < off) red[tid] = fmaxf(red[tid], red[tid + off]);
      __syncthreads();
    }
    float rowmax = red[0];
    __syncthreads();
    // pass 2: sum of exp
    float s = 0.f;
    for (int v = tid; v < VV; v += 256) s += expf(row[v] - rowmax);
    red[tid] = s; __syncthreads();
    for (int off = 128; off > 0; off >>= 1) {
      if (tid < off) red[tid] += red[tid + off];
      __syncthreads();
    }
    float lsej = rowmax + logf(red[0]);
    __syncthreads();
    // merge 256 top-5 lists -> row top5 in sv0[0..4]
#pragma unroll
    for (int q = 0; q < 5; q++) { sv0[tid * 5 + q] = tv[q]; si0[tid * 5 + q] = ti[q]; }
    __syncthreads();
    int cur = 0;
    for (int off = 128; off > 0; off >>= 1) {
      float* svc = cur ? sv1 : sv0; int* sic = cur ? si1 : si0;
      float* svn = cur ? sv0 : sv1; int* sinn = cur ? si0 : si1;
      if (tid < off) {
        int ia = 0, ib = 0;
        int baseA = tid * 5, baseB = (tid + off) * 5;
#pragma unroll
        for (int q = 0; q < 5; q++) {
          float va = svc[baseA + ia]; int xa = sic[baseA + ia];
          float vb = svc[baseB + ib]; int xb = sic[baseB + ib];
          bool ta = viBetter(va, xa, vb, xb);
          svn[baseA + q] = ta ? va : vb;
          sinn[baseA + q] = ta ? xa : xb;
          ia += ta ? 1 : 0; ib += ta ? 0 : 1;
        }
      }
      cur ^= 1;
      __syncthreads();
    }
    // 8 levels -> result lives in sv0/si0 slot 0
    if (tid == 0) {
      float cj = oc[j];
#pragma unroll
      for (int q = 0; q < 5; q++) {
        candV[j * KBM + q] = cj + (sv0[q] - lsej);  // cum + lp  (lp = logit - lse)
        candI[j * KBM + q] = j * VV + si0[q];
      }
    }
    __syncthreads();
  }

  // final top-5 over <=25 candidates (exact tie semantics via global idx)
  if (tid == 0) {
    float fv[5]; int fi[5];
#pragma unroll
    for (int q = 0; q < 5; q++) { fv[q] = -INFINITY; fi[q] = 0x7fffffff; }
    for (int t = 0; t < KBM * KBM; t++) top5_insert(fv, fi, candV[t], candI[t]);
#pragma unroll
    for (int q = 0; q < 5; q++) { selV[q] = fv[q]; selI[q] = fi[q]; }
  }
  __syncthreads();

  if (tid < KBM) {
    int p = tid, idx = selI[p];
    int bm = idx / VV, tk = idx - bm * VV;
    cum[b * KBM + p] = selV[p];
    int pf = ofin[bm];
    lengths[b * KBM + p] = olen[bm] + (pf ? 0 : 1);
    finished[b * KBM + p] = (pf || tk == EOSID) ? 1 : 0;
    last_tok[b * KBM + p] = tk;
  }
  for (int t = tid; t < KBM * MAXLEN; t += 256) {
    int p = t >> 6, pos = t & 63;
    int idx = selI[p]; int bm = idx / VV; int tk = idx - bm * VV;
    tokens[b * KBM * MAXLEN + t] = (pos == di) ? tk : ttmp[bm * MAXLEN + pos];
  }
  for (int t = tid; t < KBM * HD; t += 256) {
    int p = t >> 9, e = t & 511;
    int bm = selI[p] / VV;
    h[(size_t)(b * KBM + p) * HD + e] = A_cat[(size_t)(b * KBM + bm) * 1024 + e];
  }
}

// ---------------- first-step top-k (from replica j=0) ---------------------
__launch_bounds__(256)
__global__ void k_topk_init(const float* __restrict__ logits, float* __restrict__ cum,
                            int* __restrict__ tokens, int* __restrict__ finished,
                            int* __restrict__ lengths, int* __restrict__ last_tok,
                            float* __restrict__ h, const float* __restrict__ A_cat) {
  const int b = blockIdx.x;
  const int tid = threadIdx.x;
  __shared__ float red[256];
  __shared__ float sv0[256 * 5]; __shared__ int si0[256 * 5];
  __shared__ float sv1[256 * 5]; __shared__ int si1[256 * 5];
  const float* row = logits + (size_t)(b * KBM) * VV;   // replica j=0
  float tv[5]; int ti[5];
#pragma unroll
  for (int q = 0; q < 5; q++) { tv[q] = -INFINITY; ti[q] = 0x7fffffff; }
  float m = -INFINITY;
  for (int v = tid; v < VV; v += 256) {
    float x = row[v];
    m = fmaxf(m, x);
    top5_insert(tv, ti, x, v);
  }
  red[tid] = m; __syncthreads();
  for (int off = 128; off > 0; off >>= 1) {
    if (tid < off) red[tid] = fmaxf(red[tid], red[tid + off]);
    __syncthreads();
  }
  float rowmax = red[0];
  __syncthreads();
  float s = 0.f;
  for (int v = tid; v < VV; v += 256) s += expf(row[v] - rowmax);
  red[tid] = s; __syncthreads();
  for (int off = 128; off > 0; off >>= 1) {
    if (tid < off) red[tid] += red[tid + off];
    __syncthreads();
  }
  float lse = rowmax + logf(red[0]);
  __syncthreads();
#pragma unroll
  for (int q = 0; q < 5; q++) { sv0[tid * 5 + q] = tv[q]; si0[tid * 5 + q] = ti[q]; }
  __syncthreads();
  int cur = 0;
  for (int off = 128; off > 0; off >>= 1) {
    float* svc = cur ? sv1 : sv0; int* sic = cur ? si1 : si0;
    float* svn = cur ? sv0 : sv1; int* sinn = cur ? si0 : si1;
    if (tid < off) {
      int ia = 0, ib = 0;
      int baseA = tid * 5, baseB = (tid + off) * 5;
#pragma unroll
      for (int q = 0; q < 5; q++) {
        float va = svc[baseA + ia]; int xa = sic[baseA + ia];
        float vb = svc[baseB + ib]; int xb = sic[baseB + ib];
        bool ta = viBetter(va, xa, vb, xb);
        svn[baseA + q] = ta ? va : vb;
        sinn[baseA + q] = ta ? xa : xb;
        ia += ta ? 1 : 0; ib += ta ? 0 : 1;
      }
    }
    cur ^= 1;
    __syncthreads();
  }
  if (tid < KBM) {
    int p = tid;
    int tk = si0[p];
    cum[b * KBM + p] = sv0[p] - lse;
    finished[b * KBM + p] = (tk == EOSID) ? 1 : 0;
    lengths[b * KBM + p] = 1;
    last_tok[b * KBM + p] = tk;
    tokens[b * KBM * MAXLEN + p * MAXLEN + 0] = tk;
  }
  for (int t = tid; t < KBM * HD; t += 256) {
    int p = t >> 9, e = t & 511;
    h[(size_t)(b * KBM + p) * HD + e] = A_cat[(size_t)(b * KBM + p) * 1024 + e];
  }
}

// ---------------- final: length penalty, best beam, write outputs ---------
__global__ void k_final(const int* __restrict__ tokens, const float* __restrict__ cum,
                        const int* __restrict__ finished, const int* __restrict__ lengths,
                        float* __restrict__ out) {
  const int b = blockIdx.x;
  const int tid = threadIdx.x;  // 64 threads
  __shared__ float sv[KBM];
  __shared__ int bestIdx;
  if (tid < KBM) {
    float c = cum[b * KBM + tid];
    float pen = powf((5.0f + (float)lengths[b * KBM + tid]) / 6.0f, 1.2f);
    sv[tid] = finished[b * KBM + tid] ? (c / pen) : c;
  }
  __syncthreads();
  if (tid == 0) {
    int best = 0; float bv = sv[0];
#pragma unroll
    for (int j = 1; j < KBM; j++) {
      if (sv[j] > bv) { bv = sv[j]; best = j; }
    }
    bestIdx = best;
  }
  __syncthreads();
  out[b * MAXLEN + tid] = (float)tokens[b * KBM * MAXLEN + bestIdx * MAXLEN + tid];
  if (tid < KBM) out[BB * MAXLEN + b * KBM + tid] = cum[b * KBM + tid];
}

extern "C" void kernel_launch(void* const* d_in, const int* in_sizes, int n_in,
                              void* d_out, int out_size, void* d_ws, size_t ws_size,
                              hipStream_t stream) {
  (void)in_sizes; (void)n_in; (void)out_size; (void)ws_size;
  const int*   input_var = (const int*)d_in[0];
  const float* enc       = (const float*)d_in[1];
  const float* emb       = (const float*)d_in[2];
  const float* w_ih      = (const float*)d_in[3];
  const float* w_hh      = (const float*)d_in[4];
  const float* w_out     = (const float*)d_in[5];
  float* out = (float*)d_out;

  float* h      = (float*)d_ws;
  float* A_cat  = h + (size_t)NR * HD;
  float* logits = A_cat + (size_t)NR * 1024;
  int*   tokens = (int*)(logits + (size_t)NR * VV);
  float* cum    = (float*)(tokens + (size_t)BB * KBM * MAXLEN);
  int*   finished = (int*)(cum + NR);
  int*   lengths  = finished + NR;
  int*   last_tok = lengths + NR;

  k_init<<<64, 256, 0, stream>>>(h, tokens, last_tok, input_var);

  for (int di = 0; di < MAXLEN; di++) {
    k_gru<<<dim3(16, 5), 256, 0, stream>>>(last_tok, h, emb, w_ih, w_hh, A_cat);
    k_attn<<<NR, 256, 0, stream>>>(A_cat, enc);
    k_gemm<<<dim3(40, 5), 256, 0, stream>>>(A_cat, w_out, logits);
    if (di == 0) {
      k_topk_init<<<BB, 256, 0, stream>>>(logits, cum, tokens, finished, lengths,
                                          last_tok, h, A_cat);
    } else {
      k_topk<<<BB, 256, 0, stream>>>(logits, cum, tokens, finished, lengths,
                                     last_tok, h, A_cat, di);
    }
  }
  k_final<<<BB, 64, 0, stream>>>(tokens, cum, finished, lengths, out);
}